// Round 1
// baseline (736.316 us; speedup 1.0000x reference)
//
#include <hip/hip_runtime.h>

// FlowComposite: iterative flow composition.
// flows: [B, T, 2, H, W] fp32.  out: [B, 2, H, W] fp32.
// Per-pixel chains are independent -> one thread per (b,y,x), loop over T
// in registers, bilinear gather (padding_mode='zeros', sample at pixel-0.5).

#define FC_B 8
#define FC_T 12
#define FC_H 544
#define FC_W 960

__global__ __launch_bounds__(256) void FlowComposite_kernel(
    const float* __restrict__ flows, float* __restrict__ out)
{
    const int HW = FC_H * FC_W;
    const int N  = FC_B * HW;
    int idx = blockIdx.x * blockDim.x + threadIdx.x;
    if (idx >= N) return;

    int x = idx % FC_W;
    int r = idx / FC_W;
    int y = r % FC_H;
    int b = r / FC_H;

    float u = 0.0f, v = 0.0f;
    const float* fb = flows + (size_t)b * FC_T * 2 * HW;

    #pragma unroll 1
    for (int t = 0; t < FC_T; ++t) {
        const float* f0 = fb + (size_t)t * 2 * HW;   // channel 0 (dx)
        const float* f1 = f0 + HW;                   // channel 1 (dy)

        float px = (float)x + u - 0.5f;
        float py = (float)y + v - 0.5f;

        float x0f = floorf(px);
        float y0f = floorf(py);
        float wx1 = px - x0f;
        float wx0 = 1.0f - wx1;
        float wy1 = py - y0f;
        float wy0 = 1.0f - wy1;

        int x0 = (int)x0f;
        int y0 = (int)y0f;
        int x1 = x0 + 1;
        int y1 = y0 + 1;

        // zeros padding: validity folded into weights (branchless)
        float vx0 = (x0 >= 0 && x0 < FC_W) ? 1.0f : 0.0f;
        float vx1 = (x1 >= 0 && x1 < FC_W) ? 1.0f : 0.0f;
        float vy0 = (y0 >= 0 && y0 < FC_H) ? 1.0f : 0.0f;
        float vy1 = (y1 >= 0 && y1 < FC_H) ? 1.0f : 0.0f;

        int x0c = min(max(x0, 0), FC_W - 1);
        int x1c = min(max(x1, 0), FC_W - 1);
        int y0c = min(max(y0, 0), FC_H - 1);
        int y1c = min(max(y1, 0), FC_H - 1);

        float w00 = wx0 * wy0 * vx0 * vy0;
        float w10 = wx1 * wy0 * vx1 * vy0;
        float w01 = wx0 * wy1 * vx0 * vy1;
        float w11 = wx1 * wy1 * vx1 * vy1;

        int i00 = y0c * FC_W + x0c;
        int i10 = y0c * FC_W + x1c;
        int i01 = y1c * FC_W + x0c;
        int i11 = y1c * FC_W + x1c;

        float s0 = w00 * f0[i00] + w10 * f0[i10] + w01 * f0[i01] + w11 * f0[i11];
        float s1 = w00 * f1[i00] + w10 * f1[i10] + w01 * f1[i01] + w11 * f1[i11];

        u += s0;
        v += s1;
    }

    size_t ob = (size_t)b * 2 * HW + (size_t)y * FC_W + x;
    out[ob]      = u;   // channel 0
    out[ob + HW] = v;   // channel 1
}

extern "C" void kernel_launch(void* const* d_in, const int* in_sizes, int n_in,
                              void* d_out, int out_size, void* d_ws, size_t ws_size,
                              hipStream_t stream) {
    const float* flows = (const float*)d_in[0];
    float* out = (float*)d_out;

    const int N = FC_B * FC_H * FC_W;
    dim3 block(256);
    dim3 grid((N + 255) / 256);
    hipLaunchKernelGGL(FlowComposite_kernel, grid, block, 0, stream, flows, out);
}

// Round 4
// 733.782 us; speedup vs baseline: 1.0035x; 1.0035x over previous
//
#include <hip/hip_runtime.h>

// FlowComposite: iterative flow composition.
// flows: [B, T, 2, H, W] fp32.  out: [B, 2, H, W] fp32.
//
// R3 -> R4: revert to the EXACT R1 kernel body (bit-exact pass, absmax 0.0).
// R2/R3's 4-chain restructure changed results deterministically (0.457 in
// both, independent of fp contract setting) -> codegen-level rounding change
// amplified by the chaotic composition chain. Do NOT restructure the FP body.
// Only change vs R1: integer block->pixel swizzle so each XCD gets exactly
// one batch (grid 16320 = 8 XCDs x 2040 blocks; HW dispatch is round-robin
// blockIdx%8 -> XCD). Per-t slice/batch = 4.18 MB ~= one XCD's 4 MiB L2,
// vs R1 where every XCD touched all 8 batches (33 MB) and thrashed (FETCH
// 978 MB vs 401 MB ideal).

#define FC_B 8
#define FC_T 12
#define FC_H 544
#define FC_W 960

__global__ __launch_bounds__(256) void FlowComposite_kernel(
    const float* __restrict__ flows, float* __restrict__ out)
{
    const int HW = FC_H * FC_W;
    const int N  = FC_B * HW;

    // XCD swizzle (integer-only; FP body below is byte-identical to R1).
    // grid = 16320 blocks = 8 batches x 2040; physical blockIdx%8 ~ XCD id.
    int p = blockIdx.x;
    int L = (p & 7) * (gridDim.x >> 3) + (p >> 3);   // logical block
    int idx = L * 256 + (int)threadIdx.x;
    if (idx >= N) return;

    int x = idx % FC_W;
    int r = idx / FC_W;
    int y = r % FC_H;
    int b = r / FC_H;

    float u = 0.0f, v = 0.0f;
    const float* fb = flows + (size_t)b * FC_T * 2 * HW;

    #pragma unroll 1
    for (int t = 0; t < FC_T; ++t) {
        const float* f0 = fb + (size_t)t * 2 * HW;   // channel 0 (dx)
        const float* f1 = f0 + HW;                   // channel 1 (dy)

        float px = (float)x + u - 0.5f;
        float py = (float)y + v - 0.5f;

        float x0f = floorf(px);
        float y0f = floorf(py);
        float wx1 = px - x0f;
        float wx0 = 1.0f - wx1;
        float wy1 = py - y0f;
        float wy0 = 1.0f - wy1;

        int x0 = (int)x0f;
        int y0 = (int)y0f;
        int x1 = x0 + 1;
        int y1 = y0 + 1;

        // zeros padding: validity folded into weights (branchless)
        float vx0 = (x0 >= 0 && x0 < FC_W) ? 1.0f : 0.0f;
        float vx1 = (x1 >= 0 && x1 < FC_W) ? 1.0f : 0.0f;
        float vy0 = (y0 >= 0 && y0 < FC_H) ? 1.0f : 0.0f;
        float vy1 = (y1 >= 0 && y1 < FC_H) ? 1.0f : 0.0f;

        int x0c = min(max(x0, 0), FC_W - 1);
        int x1c = min(max(x1, 0), FC_W - 1);
        int y0c = min(max(y0, 0), FC_H - 1);
        int y1c = min(max(y1, 0), FC_H - 1);

        float w00 = wx0 * wy0 * vx0 * vy0;
        float w10 = wx1 * wy0 * vx1 * vy0;
        float w01 = wx0 * wy1 * vx0 * vy1;
        float w11 = wx1 * wy1 * vx1 * vy1;

        int i00 = y0c * FC_W + x0c;
        int i10 = y0c * FC_W + x1c;
        int i01 = y1c * FC_W + x0c;
        int i11 = y1c * FC_W + x1c;

        float s0 = w00 * f0[i00] + w10 * f0[i10] + w01 * f0[i01] + w11 * f0[i11];
        float s1 = w00 * f1[i00] + w10 * f1[i10] + w01 * f1[i01] + w11 * f1[i11];

        u += s0;
        v += s1;
    }

    size_t ob = (size_t)b * 2 * HW + (size_t)y * FC_W + x;
    out[ob]      = u;   // channel 0
    out[ob + HW] = v;   // channel 1
}

extern "C" void kernel_launch(void* const* d_in, const int* in_sizes, int n_in,
                              void* d_out, int out_size, void* d_ws, size_t ws_size,
                              hipStream_t stream) {
    const float* flows = (const float*)d_in[0];
    float* out = (float*)d_out;

    const int N = FC_B * FC_H * FC_W;    // 4,177,920
    dim3 block(256);
    dim3 grid(N / 256);                  // 16320, divisible by 8
    hipLaunchKernelGGL(FlowComposite_kernel, grid, block, 0, stream, flows, out);
}